// Round 7
// baseline (92.924 us; speedup 1.0000x reference)
//
#include <hip/hip_runtime.h>

// Problem: N=2048, M=512, D=128, all fp32.
// Outputs (flat): [0]=min_loss, [1]=wise_min_loss, [2..2+N*D)=z_out.
//
// R7: packed-FP32 (VOP3P) inner loops. gfx950 scalar v_fma issues 1 f32/lane
// per 2cyc; v_pk_*_f32 does 2 -> halves VALU issue in the hot loops.
//  - elem: pack across n-pairs: pk_add + pk_mul + 2x v_min per (2n, m).
//  - sum:  pack across d: pk_fma(z + e*(-1)) + pk_fma(dd,dd,acc) per 2 elems.
// Dispatch 1 (k_part, 512 blocks): [0,256)=elem, [256,512)=sum.
//   elem block 0 zeroes acc/counter for dispatch 2.
// Dispatch 2 (k_post, 320 blocks): [0,64)=fin, [64,320)=mask.
//
// ws layout (floats):
//   [0 .. 524288)        pb_elem[chunk][m][d]   (8*512*128, 2MB)
//   [524288 .. 540672)   pb_sum[m][32]          (512*32)
//   [540672 .. +2)       acc[2]
//   [540674]             counter (uint)

#define N_ 2048
#define M_ 512
#define D_ 128
#define PB_SUM  (8 * M_ * D_)          // 524288
#define ACC_OFF (PB_SUM + M_ * 32)     // 540672
#define CNT_OFF (ACC_OFF + 2)

typedef float v2f __attribute__((ext_vector_type(2)));

__global__ void __launch_bounds__(256, 2) k_part(
        const float* __restrict__ z, const float* __restrict__ e,
        float* __restrict__ ws) {
    const int bx = blockIdx.x;
    const int t  = threadIdx.x;

    if (bx < 256) {
        // ---- elem partials: min over one 256-n chunk for 16 m's ----
        const int mg = bx >> 3, chunk = bx & 7;
        const int d = t & 127, half = t >> 7;
        const int m0 = mg * 16 + half * 8;
        const int n0 = chunk * 256;

        v2f nege[8];
        float mnx[8], mny[8];
        #pragma unroll
        for (int k = 0; k < 8; ++k) {
            float evk = e[(m0 + k) * D_ + d];
            nege[k].x = -evk; nege[k].y = -evk;
            mnx[k] = __uint_as_float(0x7f800000u);
            mny[k] = mnx[k];
        }
        const float* zp = z + n0 * D_ + d;
        #pragma unroll 8
        for (int i = 0; i < 128; ++i) {
            v2f zz;
            zz.x = zp[(2 * i) * D_];
            zz.y = zp[(2 * i + 1) * D_];
            #pragma unroll
            for (int k = 0; k < 8; ++k) {
                v2f dd, sq;
                asm("v_pk_add_f32 %0, %1, %2" : "=v"(dd) : "v"(zz), "v"(nege[k]));
                asm("v_pk_mul_f32 %0, %1, %1" : "=v"(sq) : "v"(dd));
                mnx[k] = fminf(mnx[k], sq.x);
                mny[k] = fminf(mny[k], sq.y);
            }
        }
        float* pe = ws + (size_t)chunk * (M_ * D_) + m0 * D_ + d;
        #pragma unroll
        for (int k = 0; k < 8; ++k) pe[k * D_] = fminf(mnx[k], mny[k]);

        if (bx == 0 && t == 0) {
            ws[ACC_OFF] = 0.f;
            ws[ACC_OFF + 1] = 0.f;
            reinterpret_cast<unsigned int*>(ws)[CNT_OFF] = 0u;
        }
    } else {
        // ---- sum partials: thread owns n; packed across d ----
        const int b = bx - 256;
        const int nb = b >> 5, mt = b & 31;
        const int n = nb * 256 + t;
        const int m0 = mt * 16;

        v2f s2[16];
        #pragma unroll
        for (int k = 0; k < 16; ++k) { s2[k].x = 0.f; s2[k].y = 0.f; }
        v2f mone; mone.x = -1.f; mone.y = -1.f;

        const v2f* z2p = reinterpret_cast<const v2f*>(z) + n * 64;
        const v2f* e2p = reinterpret_cast<const v2f*>(e);

        #pragma unroll 1
        for (int dc = 0; dc < 8; ++dc) {
            v2f zz[8];
            #pragma unroll
            for (int jj = 0; jj < 8; ++jj) zz[jj] = z2p[dc * 8 + jj];
            #pragma unroll
            for (int k = 0; k < 16; ++k) {
                const v2f* ep = e2p + (m0 + k) * 64 + dc * 8;
                #pragma unroll
                for (int jj = 0; jj < 8; ++jj) {
                    v2f ev = ep[jj];                // wave-uniform broadcast
                    v2f dd;
                    asm("v_pk_fma_f32 %0, %1, %2, %3"
                        : "=v"(dd) : "v"(ev), "v"(mone), "v"(zz[jj]));
                    asm("v_pk_fma_f32 %0, %1, %1, %0"
                        : "+v"(s2[k]) : "v"(dd));
                }
            }
        }
        float s[16];
        #pragma unroll
        for (int k = 0; k < 16; ++k) s[k] = s2[k].x + s2[k].y;
        #pragma unroll
        for (int off = 32; off; off >>= 1) {
            #pragma unroll
            for (int k = 0; k < 16; ++k)
                s[k] = fminf(s[k], __shfl_xor(s[k], off));
        }
        if ((t & 63) == 0) {
            const int w = t >> 6;
            #pragma unroll
            for (int k = 0; k < 16; ++k)
                ws[PB_SUM + (m0 + k) * 32 + nb * 4 + w] = s[k];
        }
    }
}

__device__ __forceinline__ float min4(float4 v) {
    return fminf(fminf(v.x, v.y), fminf(v.z, v.w));
}

__global__ void __launch_bounds__(256, 2) k_post(
        const float* __restrict__ z, const float* __restrict__ probs,
        const float* __restrict__ drop, float* __restrict__ ws,
        float* __restrict__ out) {
    const int bx = blockIdx.x, t = threadIdx.x;

    if (bx >= 64) {
        // ---- dropout mask ----
        const int b = bx - 64;
        const int i = b * 256 + t;              // float4 index, 65536 total
        const int n = i >> 5;
        const float p = probs[n];
        const float4 zv = reinterpret_cast<const float4*>(z)[i];
        const float4 dv = reinterpret_cast<const float4*>(drop)[i];
        float2 lo, hi;
        lo.x = dv.x < p ? zv.x : 0.f;
        lo.y = dv.y < p ? zv.y : 0.f;
        hi.x = dv.z < p ? zv.z : 0.f;
        hi.y = dv.w < p ? zv.w : 0.f;
        float2* o = reinterpret_cast<float2*>(out + 2) + i * 2;
        o[0] = lo;
        o[1] = hi;
        return;
    }

    // ---- fin: reduce partials -> means -> out[0..1] ----
    const int b = bx;
    float* acc = ws + ACC_OFF;
    unsigned int* cnt = reinterpret_cast<unsigned int*>(ws) + CNT_OFF;

    // elem: min over 8 chunks of 4 cells, then local sum
    const int cell = b * 1024 + t * 4;
    float4 mv = *reinterpret_cast<const float4*>(ws + cell);
    #pragma unroll
    for (int c = 1; c < 8; ++c) {
        float4 v = *reinterpret_cast<const float4*>(ws + c * (M_ * D_) + cell);
        mv.x = fminf(mv.x, v.x); mv.y = fminf(mv.y, v.y);
        mv.z = fminf(mv.z, v.z); mv.w = fminf(mv.w, v.w);
    }
    float s_elem = (mv.x + mv.y) + (mv.z + mv.w);

    // sum path: m in [b*8, b*8+8), 8 lanes per m cover 32 partials
    float s_sum = 0.f;
    if (t < 64) {
        const int m = b * 8 + (t >> 3);
        const int j = t & 7;
        float4 v = *reinterpret_cast<const float4*>(ws + PB_SUM + m * 32 + j * 4);
        float mn = min4(v);
        mn = fminf(mn, __shfl_xor(mn, 1));
        mn = fminf(mn, __shfl_xor(mn, 2));
        mn = fminf(mn, __shfl_xor(mn, 4));
        if ((t & 7) == 0) s_sum = mn;
    }

    #pragma unroll
    for (int off = 32; off; off >>= 1) {
        s_elem += __shfl_xor(s_elem, off);
        s_sum  += __shfl_xor(s_sum, off);
    }
    __shared__ float sm[8];
    const int w = t >> 6;
    if ((t & 63) == 0) { sm[w] = s_elem; sm[4 + w] = s_sum; }
    __syncthreads();
    if (t == 0) {
        float te = sm[0] + sm[1] + sm[2] + sm[3];
        float ts = sm[4] + sm[5] + sm[6] + sm[7];
        atomicAdd(&acc[0], ts);
        atomicAdd(&acc[1], te);
        __threadfence();
        unsigned int old = atomicAdd(cnt, 1u);
        if (old == 63u) {
            float a0 = atomicAdd(&acc[0], 0.f);   // RMW read: coherent
            float a1 = atomicAdd(&acc[1], 0.f);
            out[0] = a0 * (1.0f / 512.0f);
            out[1] = a1 * (1.0f / 65536.0f);
        }
    }
}

extern "C" void kernel_launch(void* const* d_in, const int* in_sizes, int n_in,
                              void* d_out, int out_size, void* d_ws, size_t ws_size,
                              hipStream_t stream) {
    const float* z     = (const float*)d_in[0];
    const float* e     = (const float*)d_in[1];
    const float* probs = (const float*)d_in[2];
    const float* drop  = (const float*)d_in[3];
    float* out = (float*)d_out;
    float* ws  = (float*)d_ws;

    k_part<<<dim3(512), dim3(256), 0, stream>>>(z, e, ws);
    k_post<<<dim3(320), dim3(256), 0, stream>>>(z, probs, drop, ws, out);
}